// Round 2
// baseline (1057.362 us; speedup 1.0000x reference)
//
#include <hip/hip_runtime.h>
#include <hip/hip_bf16.h>
#include <stdint.h>

#define T_TOK 16384
#define CDIM  1024
#define ENUM_ 8
#define INTER_ 2730
#define IPAD  2752      // INTER padded to x64
#define NGU   5460
#define NGUPAD 5504     // 2*IPAD: [g | u] each padded to 2752
#define CAP   2560
#define EGRP  4         // experts per GEMM dispatch (blockIdx.z)
#define CSTRIDE 64      // u32 stride between padded per-expert counters (256B)

typedef __attribute__((ext_vector_type(8))) short short8;
typedef __attribute__((ext_vector_type(4))) float f32x4;
typedef unsigned long long u64;
typedef unsigned int u32;

static __device__ __forceinline__ ushort f2bf(float f){
  u32 u = __float_as_uint(f);
  u32 r = u + 0x7FFFu + ((u >> 16) & 1u);
  return (ushort)(r >> 16);
}

// async global->LDS, 16B per lane. LDS dest = wave-uniform base + lane*16.
static __device__ __forceinline__ void glds16(const void* g, void* l){
  __builtin_amdgcn_global_load_lds(
      (const __attribute__((address_space(1))) void*)g,
      (__attribute__((address_space(3))) void*)l, 16, 0, 0);
}

// ---------- weight transposes ----------
__global__ void k_tr_wgu(const float* __restrict__ wgu, ushort* __restrict__ wguT){
  __shared__ float tile[32][33];
  const int e = blockIdx.z;
  const int k0 = blockIdx.x*32, n0 = blockIdx.y*32;
  const float* src = wgu + (size_t)e*CDIM*NGU;
  ushort* dst = wguT + (size_t)e*NGUPAD*CDIM;
  const int tx = threadIdx.x, ty = threadIdx.y;
  #pragma unroll
  for (int r = ty; r < 32; r += 8){
    int n = n0 + tx;
    int j = (n < IPAD) ? n : n - (IPAD - INTER_);
    bool valid = (n < INTER_) || (n >= IPAD && j < NGU);
    tile[r][tx] = valid ? src[(size_t)(k0 + r)*NGU + j] : 0.f;
  }
  __syncthreads();
  #pragma unroll
  for (int r = ty; r < 32; r += 8)
    dst[(size_t)(n0 + r)*CDIM + k0 + tx] = f2bf(tile[tx][r]);
}

__global__ void k_tr_dwn(const float* __restrict__ dw, ushort* __restrict__ dwT){
  __shared__ float tile[32][33];
  const int e = blockIdx.z;
  const int k0 = blockIdx.x*32, n0 = blockIdx.y*32;
  const float* src = dw + (size_t)e*INTER_*CDIM;
  ushort* dst = dwT + (size_t)e*CDIM*IPAD;
  const int tx = threadIdx.x, ty = threadIdx.y;
  #pragma unroll
  for (int r = ty; r < 32; r += 8){
    int k = k0 + r;
    tile[r][tx] = (k < INTER_) ? src[(size_t)k*CDIM + n0 + tx] : 0.f;
  }
  __syncthreads();
  #pragma unroll
  for (int r = ty; r < 32; r += 8)
    dst[(size_t)(n0 + r)*IPAD + k0 + tx] = f2bf(tile[tx][r]);
}

// ---------- gating ----------
__global__ void k_cond(const float* __restrict__ cond, const float* __restrict__ gate_w,
                       float* __restrict__ condlog){
  const int b = blockIdx.x;
  const int wave = threadIdx.x >> 6, lane = threadIdx.x & 63;
  float a0 = 0.f, a1 = 0.f;
  for (int c = lane; c < CDIM; c += 64){
    float cv = cond[(size_t)b*CDIM + c];
    const float* g = gate_w + (size_t)(CDIM + c)*8;
    a0 += cv * g[2*wave]; a1 += cv * g[2*wave + 1];
  }
  #pragma unroll
  for (int off = 32; off; off >>= 1){
    a0 += __shfl_down(a0, off, 64);
    a1 += __shfl_down(a1, off, 64);
  }
  if (lane == 0){
    condlog[b*8 + 2*wave]     = a0;
    condlog[b*8 + 2*wave + 1] = a1;
  }
}

// Gate logits with LDS-cached transposed gate_w. float4 x loads + float4 LDS
// reads + ushort4 xb stores. Entry emission is BLOCK-AGGREGATED (round-1 win:
// 400us -> off the profile): LDS-atomic local positions, one global atomicAdd
// per expert per block on 256B-strided counters.
__global__ __launch_bounds__(256) void k_gate(
    const float* __restrict__ x, const float* __restrict__ gate_w,
    const float* __restrict__ condlog, const float* __restrict__ snr,
    u32* __restrict__ pcnt, u64* __restrict__ entries, ushort* __restrict__ xb){
  __shared__ float gwT[8*1024];
  __shared__ u32 lcnt[8];
  __shared__ u32 lbase[8];
  __shared__ u64 keybuf[32];
  __shared__ u32 posbuf[32];   // (expert<<16) | local_pos
  const int tid = threadIdx.x;
  if (tid < 8) lcnt[tid] = 0;
  for (int idx = tid; idx < 8192; idx += 256){
    float v = gate_w[idx];                    // coalesced read, [c][e] flat
    gwT[(idx & 7)*1024 + (idx >> 3)] = v;     // transpose into [e][c] (once)
  }
  __syncthreads();
  const int wave = tid >> 6, lane = tid & 63;
  const int tbase = blockIdx.x*16 + wave*4;
  #pragma unroll 1
  for (int it = 0; it < 4; ++it){
    const int t = tbase + it;
    const int b = t >> 12;                    // N = 4096 tokens/batch
    float acc[8] = {0,0,0,0,0,0,0,0};
    #pragma unroll
    for (int i = 0; i < 4; ++i){
      const int c = lane*4 + 256*i;
      const float4 xv = *(const float4*)(x + (size_t)t*CDIM + c);
      ushort4 xo;
      xo.x = f2bf(xv.x); xo.y = f2bf(xv.y); xo.z = f2bf(xv.z); xo.w = f2bf(xv.w);
      *(ushort4*)(xb + (size_t)t*CDIM + c) = xo;
      #pragma unroll
      for (int e = 0; e < 8; ++e){
        const float4 gv = *(const float4*)(gwT + e*1024 + c);
        acc[e] += xv.x*gv.x + xv.y*gv.y + xv.z*gv.z + xv.w*gv.w;
      }
    }
    #pragma unroll
    for (int e = 0; e < 8; ++e)
      #pragma unroll
      for (int off = 32; off; off >>= 1)
        acc[e] += __shfl_down(acc[e], off, 64);
    if (lane == 0){
      bool hn = snr[b] < 0.5f;
      float lg[8];
      #pragma unroll
      for (int e = 0; e < 8; ++e) lg[e] = acc[e] + condlog[b*8 + e];
      float mx = -1e30f;
      #pragma unroll
      for (int e = 0; e < 8; ++e) if (!(hn && e >= 2) && lg[e] > mx) mx = lg[e];
      float p[8]; float s = 0.f;
      #pragma unroll
      for (int e = 0; e < 8; ++e){ p[e] = (hn && e >= 2) ? 0.f : expf(lg[e] - mx); s += p[e]; }
      float inv_ = 1.f / s;
      #pragma unroll
      for (int e = 0; e < 8; ++e) p[e] *= inv_;
      int i0 = 0;
      #pragma unroll
      for (int e = 1; e < 8; ++e) if (p[e] > p[i0]) i0 = e;
      int i1 = -1; float pv1 = -1.f;
      #pragma unroll
      for (int e = 0; e < 8; ++e) if (e != i0 && p[e] > pv1){ pv1 = p[e]; i1 = e; }
      float v0 = p[i0], v1 = pv1;
      float den = fmaxf(v0 + v1, 1e-12f);
      v0 /= den; v1 /= den;
      u32 flat0 = (u32)(t*2);
      const int slot = wave*4 + it;
      u32 p0 = atomicAdd(&lcnt[i0], 1u);   // LDS atomic: fast, local
      u32 p1 = atomicAdd(&lcnt[i1], 1u);
      keybuf[2*slot]     = ((u64)__float_as_uint(v0) << 32) | (u64)(0xFFFFFFFFu - flat0);
      posbuf[2*slot]     = ((u32)i0 << 16) | p0;
      keybuf[2*slot + 1] = ((u64)__float_as_uint(v1) << 32) | (u64)(0xFFFFFFFFu - (flat0 + 1u));
      posbuf[2*slot + 1] = ((u32)i1 << 16) | p1;
    }
  }
  __syncthreads();
  if (tid < 8) lbase[tid] = atomicAdd(&pcnt[tid*CSTRIDE], lcnt[tid]);
  __syncthreads();
  if (tid < 32){
    u32 pe = posbuf[tid];
    int e = (int)(pe >> 16);
    u32 pos = pe & 0xFFFFu;
    entries[(size_t)e*T_TOK + lbase[e] + pos] = keybuf[tid];
  }
}

// ---------- capacity selection (exact top-k via unique 64b keys) ----------
__global__ void k_select(const u32* __restrict__ pcnt, const u64* __restrict__ entries,
                         u64* __restrict__ thresh){
  const int e = blockIdx.x;
  const int n = (int)pcnt[e*CSTRIDE];
  if (n <= CAP){ if (threadIdx.x == 0) thresh[e] = 0ull; return; }
  const u64* keys = entries + (size_t)e*T_TOK;
  __shared__ u32 hist[256];
  __shared__ u64 spfx;
  __shared__ int srem;
  u64 prefix = 0, pmask = 0;
  int rem = CAP;
  for (int d = 7; d >= 0; --d){
    const int sh = d*8;
    hist[threadIdx.x] = 0;
    __syncthreads();
    for (int i = threadIdx.x; i < n; i += 256){
      u64 k = keys[i];
      if ((k & pmask) == prefix)
        atomicAdd(&hist[(u32)((k >> sh) & 0xFFull)], 1u);
    }
    __syncthreads();
    if (threadIdx.x == 0){
      int c = 0, chosen = 0, nr = rem;
      for (int v = 255; v >= 0; --v){
        int nc = c + (int)hist[v];
        if (nc >= rem){ chosen = v; nr = rem - c; break; }
        c = nc;
      }
      spfx = prefix | ((u64)(u32)chosen << sh);
      srem = nr;
    }
    __syncthreads();
    prefix = spfx; rem = srem; pmask |= (0xFFull << sh);
  }
  if (threadIdx.x == 0) thresh[e] = prefix;
}

// Compact survivors AND build the inverse map: for each token, up to 2
// (expert,slot) refs. Removes the need for atomics in the gemm2 epilogue.
__global__ void k_compact(const u32* __restrict__ pcnt, const u64* __restrict__ entries,
                          const u64* __restrict__ thresh, u32* __restrict__ mcnt,
                          int* __restrict__ tokbuf, float* __restrict__ wgtbuf,
                          u32* __restrict__ invcnt, u32* __restrict__ inv){
  const int e = blockIdx.y;
  const int n = (int)pcnt[e*CSTRIDE];
  const u64 th = thresh[e];
  const u64* keys = entries + (size_t)e*T_TOK;
  for (int i = blockIdx.x*256 + threadIdx.x; i < n; i += gridDim.x*256){
    u64 k = keys[i];
    if (k >= th){
      u32 pos = atomicAdd(&mcnt[e], 1u);
      u32 flat = 0xFFFFFFFFu - (u32)(k & 0xFFFFFFFFull);
      int t = (int)(flat >> 1);
      tokbuf[(size_t)e*CAP + pos] = t;
      wgtbuf[(size_t)e*CAP + pos] = __uint_as_float((u32)(k >> 32));
      u32 ic = atomicAdd(&invcnt[t], 1u);          // <=2 per token, distinct addrs
      inv[2*t + ic] = ((u32)e << 12) | pos;        // pos < 2560 fits 12 bits
    }
  }
}

// ---------- expert GEMMs, m97 structure ----------
__global__ __launch_bounds__(256) void k_gemm1(
    const ushort* __restrict__ xb, const ushort* __restrict__ wguT_g,
    const int* __restrict__ tok_g, const u32* __restrict__ mcnt_g,
    ushort* __restrict__ h_g){
  const int z = blockIdx.z;
  const int m_e = (int)mcnt_g[z];
  const int m0 = blockIdx.x * 128;
  if (m0 >= m_e) return;
  const ushort* wguT = wguT_g + (size_t)z*NGUPAD*CDIM;
  const int* tok = tok_g + (size_t)z*CAP;
  ushort* h = h_g + (size_t)z*CAP*IPAD;
  const int j0 = blockIdx.y * 64;

  __shared__ ushort As[128*32];
  __shared__ ushort Bg[64*32];
  __shared__ ushort Bu[64*32];
  const int tid = threadIdx.x;
  const int lane = tid & 63, wave = tid >> 6;
  const int wm = wave >> 1, wn = wave & 1;
  const int lm = lane & 15, quad = lane >> 4;

  const int af0 = tid*8, af1 = tid*8 + 2048;
  const ushort* ag0 = xb + (size_t)tok[m0 + (af0 >> 5)]*CDIM + (af0 & 31);
  const ushort* ag1 = xb + (size_t)tok[m0 + (af1 >> 5)]*CDIM + (af1 & 31);
  const int br = tid >> 2, bc = (tid & 3)*8;
  const ushort* bgp = wguT + (size_t)(j0 + br)*CDIM + bc;
  const ushort* bup = wguT + (size_t)(IPAD + j0 + br)*CDIM + bc;

  f32x4 accg[4][2], accu[4][2];
  #pragma unroll
  for (int i = 0; i < 4; ++i)
    #pragma unroll
    for (int j = 0; j < 2; ++j){
      accg[i][j] = (f32x4){0.f,0.f,0.f,0.f};
      accu[i][j] = (f32x4){0.f,0.f,0.f,0.f};
    }

  for (int k0 = 0; k0 < CDIM; k0 += 32){
    glds16(ag0 + k0, As + af0);
    glds16(ag1 + k0, As + af1);
    glds16(bgp + k0, Bg + tid*8);
    glds16(bup + k0, Bu + tid*8);
    __syncthreads();
    short8 a[4], vg[2], vu[2];
    #pragma unroll
    for (int mt = 0; mt < 4; ++mt)
      a[mt] = *(const short8*)(As + (wm*64 + mt*16 + lm)*32 + quad*8);
    #pragma unroll
    for (int nt = 0; nt < 2; ++nt){
      vg[nt] = *(const short8*)(Bg + (wn*32 + nt*16 + lm)*32 + quad*8);
      vu[nt] = *(const short8*)(Bu + (wn*32 + nt*16 + lm)*32 + quad*8);
    }
    __syncthreads();
    #pragma unroll
    for (int mt = 0; mt < 4; ++mt)
      #pragma unroll
      for (int nt = 0; nt < 2; ++nt){
        accg[mt][nt] = __builtin_amdgcn_mfma_f32_16x16x32_bf16(a[mt], vg[nt], accg[mt][nt], 0, 0, 0);
        accu[mt][nt] = __builtin_amdgcn_mfma_f32_16x16x32_bf16(a[mt], vu[nt], accu[mt][nt], 0, 0, 0);
      }
  }
  #pragma unroll
  for (int mt = 0; mt < 4; ++mt)
    #pragma unroll
    for (int nt = 0; nt < 2; ++nt)
      #pragma unroll
      for (int r = 0; r < 4; ++r){
        int row = m0 + wm*64 + mt*16 + quad*4 + r;
        int col = j0 + wn*32 + nt*16 + lm;
        float g = accg[mt][nt][r];
        float uu = accu[mt][nt][r];
        float sg = g / (1.f + __expf(-g));
        h[(size_t)row*IPAD + col] = f2bf(sg * uu);
      }
}

// Pure GEMM now: y[e][slot][C] f32, plain stores (round-2: removed 21M
// f32 atomicAdds to scattered token rows; combine moved to k_out).
__global__ __launch_bounds__(256) void k_gemm2(
    const ushort* __restrict__ h_g, const ushort* __restrict__ dwT_g,
    const u32* __restrict__ mcnt_g, float* __restrict__ y_g){
  const int z = blockIdx.z;
  const int m_e = (int)mcnt_g[z];
  const int m0 = blockIdx.x * 128;
  if (m0 >= m_e) return;
  const ushort* h = h_g + (size_t)z*CAP*IPAD;
  const ushort* dwT = dwT_g + (size_t)z*CDIM*IPAD;
  const int n0 = blockIdx.y * 128;

  __shared__ ushort As[128*32];
  __shared__ ushort Bs[128*32];
  const int tid = threadIdx.x;
  const int lane = tid & 63, wave = tid >> 6;
  const int wm = wave >> 1, wn = wave & 1;
  const int lm = lane & 15, quad = lane >> 4;

  const int af0 = tid*8, af1 = tid*8 + 2048;
  const ushort* ap0 = h + (size_t)(m0 + (af0 >> 5))*IPAD + (af0 & 31);
  const ushort* ap1 = h + (size_t)(m0 + (af1 >> 5))*IPAD + (af1 & 31);
  const ushort* bp0 = dwT + (size_t)(n0 + (af0 >> 5))*IPAD + (af0 & 31);
  const ushort* bp1 = dwT + (size_t)(n0 + (af1 >> 5))*IPAD + (af1 & 31);

  f32x4 acc[4][4];
  #pragma unroll
  for (int i = 0; i < 4; ++i)
    #pragma unroll
    for (int j = 0; j < 4; ++j) acc[i][j] = (f32x4){0.f,0.f,0.f,0.f};

  for (int k0 = 0; k0 < IPAD; k0 += 32){
    glds16(ap0 + k0, As + af0);
    glds16(ap1 + k0, As + af1);
    glds16(bp0 + k0, Bs + af0);
    glds16(bp1 + k0, Bs + af1);
    __syncthreads();
    short8 a[4], b[4];
    #pragma unroll
    for (int mt = 0; mt < 4; ++mt)
      a[mt] = *(const short8*)(As + (wm*64 + mt*16 + lm)*32 + quad*8);
    #pragma unroll
    for (int nt = 0; nt < 4; ++nt)
      b[nt] = *(const short8*)(Bs + (wn*64 + nt*16 + lm)*32 + quad*8);
    __syncthreads();
    #pragma unroll
    for (int mt = 0; mt < 4; ++mt)
      #pragma unroll
      for (int nt = 0; nt < 4; ++nt)
        acc[mt][nt] = __builtin_amdgcn_mfma_f32_16x16x32_bf16(a[mt], b[nt], acc[mt][nt], 0, 0, 0);
  }
  #pragma unroll
  for (int mt = 0; mt < 4; ++mt)
    #pragma unroll
    for (int r = 0; r < 4; ++r){
      int row = m0 + wm*64 + mt*16 + quad*4 + r;
      float* yrow = y_g + ((size_t)z*CAP + row)*CDIM;
      #pragma unroll
      for (int nt = 0; nt < 4; ++nt){
        int col = n0 + wn*64 + nt*16 + lm;
        yrow[col] = acc[mt][nt][r];
      }
    }
}

// Combine: out[t] = sum_j w_j * y[e_j][slot_j][:]. Writes every token row
// (tokens dropped by capacity -> zeros), so no out memset needed.
__global__ __launch_bounds__(256) void k_out(
    const float* __restrict__ ybuf, const u32* __restrict__ inv,
    const u32* __restrict__ invcnt, const float* __restrict__ wgtbuf,
    float* __restrict__ out){
  const int t = blockIdx.x*4 + (threadIdx.x >> 6);
  const int lane = threadIdx.x & 63;
  const int n = (int)invcnt[t];
  f32x4 acc[4];
  #pragma unroll
  for (int i = 0; i < 4; ++i) acc[i] = (f32x4){0.f,0.f,0.f,0.f};
  for (int j = 0; j < n; ++j){
    u32 v = inv[2*t + j];
    int e = (int)(v >> 12);
    int pos = (int)(v & 0xFFFu);
    float w = wgtbuf[e*CAP + pos];
    const float* yr = ybuf + ((size_t)e*CAP + pos)*CDIM;
    #pragma unroll
    for (int i = 0; i < 4; ++i){
      f32x4 yv = *(const f32x4*)(yr + i*256 + lane*4);
      acc[i] += yv * w;
    }
  }
  float* orow = out + (size_t)t*CDIM;
  #pragma unroll
  for (int i = 0; i < 4; ++i)
    *(f32x4*)(orow + i*256 + lane*4) = acc[i];
}

extern "C" void kernel_launch(void* const* d_in, const int* in_sizes, int n_in,
                              void* d_out, int out_size, void* d_ws, size_t ws_size,
                              hipStream_t stream){
  const float* x      = (const float*)d_in[0];
  const float* cond   = (const float*)d_in[1];
  const float* snr    = (const float*)d_in[2];
  const float* gate_w = (const float*)d_in[3];
  const float* wgu    = (const float*)d_in[4];
  const float* wdn    = (const float*)d_in[5];
  float* out = (float*)d_out;
  (void)in_sizes; (void)n_in; (void)ws_size; (void)out_size;

  char* ws = (char*)d_ws;
  size_t off = 0;
  auto take = [&](size_t bytes) -> char* {
    char* p = ws + off;
    off += (bytes + 255) & ~(size_t)255;
    return p;
  };
  u32* pcnt     = (u32*)take(8*CSTRIDE*4);   // 2048B, 256B-strided counters
  u32* mcnt     = (u32*)take(256);           // 8 x u32
  float* condlog = (float*)take(256);        // 32 x f32
  u64* thresh   = (u64*)take(256);           // 8 x u64
  u32* invcnt   = (u32*)take((size_t)T_TOK*4);     // 64KB, contiguous w/ ctrl
  u32* inv      = (u32*)take((size_t)T_TOK*2*4);   // 128KB (written before read)
  u64* entries  = (u64*)take((size_t)ENUM_*T_TOK*8);
  int* tokbuf   = (int*)take((size_t)ENUM_*CAP*4);
  float* wgtbuf = (float*)take((size_t)ENUM_*CAP*4);
  ushort* xb    = (ushort*)take((size_t)T_TOK*CDIM*2);
  ushort* wguT  = (ushort*)take((size_t)ENUM_*NGUPAD*CDIM*2);
  ushort* dwT   = (ushort*)take((size_t)ENUM_*CDIM*IPAD*2);
  ushort* hbuf  = (ushort*)take((size_t)EGRP*CAP*IPAD*2);
  float* ybuf   = (float*)take((size_t)ENUM_*CAP*CDIM*4);

  // pcnt..invcnt are contiguous takes: 2048+256+256+256+65536 = 68352 bytes
  hipMemsetAsync(pcnt, 0, 68352, stream);
  hipMemsetAsync(tokbuf, 0, (size_t)ENUM_*CAP*4, stream);  // padded slots -> token 0

  k_cond<<<4, 256, 0, stream>>>(cond, gate_w, condlog);
  k_gate<<<T_TOK/16, 256, 0, stream>>>(x, gate_w, condlog, snr, pcnt, entries, xb);
  k_tr_wgu<<<dim3(CDIM/32, NGUPAD/32, ENUM_), dim3(32,8), 0, stream>>>(wgu, wguT);
  k_tr_dwn<<<dim3(IPAD/32, CDIM/32, ENUM_), dim3(32,8), 0, stream>>>(wdn, dwT);
  k_select<<<ENUM_, 256, 0, stream>>>(pcnt, entries, thresh);
  k_compact<<<dim3(64, ENUM_), 256, 0, stream>>>(pcnt, entries, thresh, mcnt,
                                                 tokbuf, wgtbuf, invcnt, inv);

  for (int g = 0; g < ENUM_/EGRP; ++g){
    k_gemm1<<<dim3(CAP/128, IPAD/64, EGRP), 256, 0, stream>>>(
        xb, wguT + (size_t)g*EGRP*NGUPAD*CDIM,
        tokbuf + (size_t)g*EGRP*CAP, mcnt + g*EGRP, hbuf);
    k_gemm2<<<dim3(CAP/128, CDIM/128, EGRP), 256, 0, stream>>>(
        hbuf, dwT + (size_t)g*EGRP*CDIM*IPAD,
        mcnt + g*EGRP, ybuf + (size_t)g*EGRP*CAP*CDIM);
  }
  k_out<<<T_TOK/4, 256, 0, stream>>>(ybuf, inv, invcnt, wgtbuf, out);
}

// Round 3
// 1054.628 us; speedup vs baseline: 1.0026x; 1.0026x over previous
//
#include <hip/hip_runtime.h>
#include <hip/hip_bf16.h>
#include <stdint.h>

#define T_TOK 16384
#define CDIM  1024
#define ENUM_ 8
#define INTER_ 2730
#define IPAD  2752      // INTER padded to x64
#define NGU   5460
#define NGUPAD 5504     // 2*IPAD: [g | u] each padded to 2752
#define CAP   2560
#define EGRP  4         // experts per GEMM dispatch (blockIdx.z)
#define CSTRIDE 64      // u32 stride between padded per-expert counters (256B)

typedef __attribute__((ext_vector_type(8))) short short8;
typedef __attribute__((ext_vector_type(4))) float f32x4;
typedef unsigned long long u64;
typedef unsigned int u32;

static __device__ __forceinline__ ushort f2bf(float f){
  u32 u = __float_as_uint(f);
  u32 r = u + 0x7FFFu + ((u >> 16) & 1u);
  return (ushort)(r >> 16);
}

// async global->LDS, 16B per lane. LDS dest = wave-uniform base + lane*16.
static __device__ __forceinline__ void glds16(const void* g, void* l){
  __builtin_amdgcn_global_load_lds(
      (const __attribute__((address_space(1))) void*)g,
      (__attribute__((address_space(3))) void*)l, 16, 0, 0);
}

// ---------- weight transposes ----------
__global__ void k_tr_wgu(const float* __restrict__ wgu, ushort* __restrict__ wguT){
  __shared__ float tile[32][33];
  const int e = blockIdx.z;
  const int k0 = blockIdx.x*32, n0 = blockIdx.y*32;
  const float* src = wgu + (size_t)e*CDIM*NGU;
  ushort* dst = wguT + (size_t)e*NGUPAD*CDIM;
  const int tx = threadIdx.x, ty = threadIdx.y;
  #pragma unroll
  for (int r = ty; r < 32; r += 8){
    int n = n0 + tx;
    int j = (n < IPAD) ? n : n - (IPAD - INTER_);
    bool valid = (n < INTER_) || (n >= IPAD && j < NGU);
    tile[r][tx] = valid ? src[(size_t)(k0 + r)*NGU + j] : 0.f;
  }
  __syncthreads();
  #pragma unroll
  for (int r = ty; r < 32; r += 8)
    dst[(size_t)(n0 + r)*CDIM + k0 + tx] = f2bf(tile[tx][r]);
}

__global__ void k_tr_dwn(const float* __restrict__ dw, ushort* __restrict__ dwT){
  __shared__ float tile[32][33];
  const int e = blockIdx.z;
  const int k0 = blockIdx.x*32, n0 = blockIdx.y*32;
  const float* src = dw + (size_t)e*INTER_*CDIM;
  ushort* dst = dwT + (size_t)e*CDIM*IPAD;
  const int tx = threadIdx.x, ty = threadIdx.y;
  #pragma unroll
  for (int r = ty; r < 32; r += 8){
    int k = k0 + r;
    tile[r][tx] = (k < INTER_) ? src[(size_t)k*CDIM + n0 + tx] : 0.f;
  }
  __syncthreads();
  #pragma unroll
  for (int r = ty; r < 32; r += 8)
    dst[(size_t)(n0 + r)*IPAD + k0 + tx] = f2bf(tile[tx][r]);
}

// ---------- gating ----------
__global__ void k_cond(const float* __restrict__ cond, const float* __restrict__ gate_w,
                       float* __restrict__ condlog){
  const int b = blockIdx.x;
  const int wave = threadIdx.x >> 6, lane = threadIdx.x & 63;
  float a0 = 0.f, a1 = 0.f;
  for (int c = lane; c < CDIM; c += 64){
    float cv = cond[(size_t)b*CDIM + c];
    const float* g = gate_w + (size_t)(CDIM + c)*8;
    a0 += cv * g[2*wave]; a1 += cv * g[2*wave + 1];
  }
  #pragma unroll
  for (int off = 32; off; off >>= 1){
    a0 += __shfl_down(a0, off, 64);
    a1 += __shfl_down(a1, off, 64);
  }
  if (lane == 0){
    condlog[b*8 + 2*wave]     = a0;
    condlog[b*8 + 2*wave + 1] = a1;
  }
}

// Gate logits with LDS-cached transposed gate_w. float4 x loads + float4 LDS
// reads + ushort4 xb stores. Entry emission is BLOCK-AGGREGATED (round-1 win:
// 400us -> off the profile): LDS-atomic local positions, one global atomicAdd
// per expert per block on 256B-strided counters.
__global__ __launch_bounds__(256) void k_gate(
    const float* __restrict__ x, const float* __restrict__ gate_w,
    const float* __restrict__ condlog, const float* __restrict__ snr,
    u32* __restrict__ pcnt, u64* __restrict__ entries, ushort* __restrict__ xb){
  __shared__ float gwT[8*1024];
  __shared__ u32 lcnt[8];
  __shared__ u32 lbase[8];
  __shared__ u64 keybuf[32];
  __shared__ u32 posbuf[32];   // (expert<<16) | local_pos
  const int tid = threadIdx.x;
  if (tid < 8) lcnt[tid] = 0;
  for (int idx = tid; idx < 8192; idx += 256){
    float v = gate_w[idx];                    // coalesced read, [c][e] flat
    gwT[(idx & 7)*1024 + (idx >> 3)] = v;     // transpose into [e][c] (once)
  }
  __syncthreads();
  const int wave = tid >> 6, lane = tid & 63;
  const int tbase = blockIdx.x*16 + wave*4;
  #pragma unroll 1
  for (int it = 0; it < 4; ++it){
    const int t = tbase + it;
    const int b = t >> 12;                    // N = 4096 tokens/batch
    float acc[8] = {0,0,0,0,0,0,0,0};
    #pragma unroll
    for (int i = 0; i < 4; ++i){
      const int c = lane*4 + 256*i;
      const float4 xv = *(const float4*)(x + (size_t)t*CDIM + c);
      ushort4 xo;
      xo.x = f2bf(xv.x); xo.y = f2bf(xv.y); xo.z = f2bf(xv.z); xo.w = f2bf(xv.w);
      *(ushort4*)(xb + (size_t)t*CDIM + c) = xo;
      #pragma unroll
      for (int e = 0; e < 8; ++e){
        const float4 gv = *(const float4*)(gwT + e*1024 + c);
        acc[e] += xv.x*gv.x + xv.y*gv.y + xv.z*gv.z + xv.w*gv.w;
      }
    }
    #pragma unroll
    for (int e = 0; e < 8; ++e)
      #pragma unroll
      for (int off = 32; off; off >>= 1)
        acc[e] += __shfl_down(acc[e], off, 64);
    if (lane == 0){
      bool hn = snr[b] < 0.5f;
      float lg[8];
      #pragma unroll
      for (int e = 0; e < 8; ++e) lg[e] = acc[e] + condlog[b*8 + e];
      float mx = -1e30f;
      #pragma unroll
      for (int e = 0; e < 8; ++e) if (!(hn && e >= 2) && lg[e] > mx) mx = lg[e];
      float p[8]; float s = 0.f;
      #pragma unroll
      for (int e = 0; e < 8; ++e){ p[e] = (hn && e >= 2) ? 0.f : expf(lg[e] - mx); s += p[e]; }
      float inv_ = 1.f / s;
      #pragma unroll
      for (int e = 0; e < 8; ++e) p[e] *= inv_;
      int i0 = 0;
      #pragma unroll
      for (int e = 1; e < 8; ++e) if (p[e] > p[i0]) i0 = e;
      int i1 = -1; float pv1 = -1.f;
      #pragma unroll
      for (int e = 0; e < 8; ++e) if (e != i0 && p[e] > pv1){ pv1 = p[e]; i1 = e; }
      float v0 = p[i0], v1 = pv1;
      float den = fmaxf(v0 + v1, 1e-12f);
      v0 /= den; v1 /= den;
      u32 flat0 = (u32)(t*2);
      const int slot = wave*4 + it;
      u32 p0 = atomicAdd(&lcnt[i0], 1u);   // LDS atomic: fast, local
      u32 p1 = atomicAdd(&lcnt[i1], 1u);
      keybuf[2*slot]     = ((u64)__float_as_uint(v0) << 32) | (u64)(0xFFFFFFFFu - flat0);
      posbuf[2*slot]     = ((u32)i0 << 16) | p0;
      keybuf[2*slot + 1] = ((u64)__float_as_uint(v1) << 32) | (u64)(0xFFFFFFFFu - (flat0 + 1u));
      posbuf[2*slot + 1] = ((u32)i1 << 16) | p1;
    }
  }
  __syncthreads();
  if (tid < 8) lbase[tid] = atomicAdd(&pcnt[tid*CSTRIDE], lcnt[tid]);
  __syncthreads();
  if (tid < 32){
    u32 pe = posbuf[tid];
    int e = (int)(pe >> 16);
    u32 pos = pe & 0xFFFFu;
    entries[(size_t)e*T_TOK + lbase[e] + pos] = keybuf[tid];
  }
}

// ---------- capacity selection (exact top-k via unique 64b keys) ----------
__global__ void k_select(const u32* __restrict__ pcnt, const u64* __restrict__ entries,
                         u64* __restrict__ thresh){
  const int e = blockIdx.x;
  const int n = (int)pcnt[e*CSTRIDE];
  if (n <= CAP){ if (threadIdx.x == 0) thresh[e] = 0ull; return; }
  const u64* keys = entries + (size_t)e*T_TOK;
  __shared__ u32 hist[256];
  __shared__ u64 spfx;
  __shared__ int srem;
  u64 prefix = 0, pmask = 0;
  int rem = CAP;
  for (int d = 7; d >= 0; --d){
    const int sh = d*8;
    hist[threadIdx.x] = 0;
    __syncthreads();
    for (int i = threadIdx.x; i < n; i += 256){
      u64 k = keys[i];
      if ((k & pmask) == prefix)
        atomicAdd(&hist[(u32)((k >> sh) & 0xFFull)], 1u);
    }
    __syncthreads();
    if (threadIdx.x == 0){
      int c = 0, chosen = 0, nr = rem;
      for (int v = 255; v >= 0; --v){
        int nc = c + (int)hist[v];
        if (nc >= rem){ chosen = v; nr = rem - c; break; }
        c = nc;
      }
      spfx = prefix | ((u64)(u32)chosen << sh);
      srem = nr;
    }
    __syncthreads();
    prefix = spfx; rem = srem; pmask |= (0xFFull << sh);
  }
  if (threadIdx.x == 0) thresh[e] = prefix;
}

// Compact survivors AND build the inverse map: for each token, up to 2
// (expert,slot) refs. Removes the need for atomics in the gemm2 epilogue.
__global__ void k_compact(const u32* __restrict__ pcnt, const u64* __restrict__ entries,
                          const u64* __restrict__ thresh, u32* __restrict__ mcnt,
                          int* __restrict__ tokbuf, float* __restrict__ wgtbuf,
                          u32* __restrict__ invcnt, u32* __restrict__ inv){
  const int e = blockIdx.y;
  const int n = (int)pcnt[e*CSTRIDE];
  const u64 th = thresh[e];
  const u64* keys = entries + (size_t)e*T_TOK;
  for (int i = blockIdx.x*256 + threadIdx.x; i < n; i += gridDim.x*256){
    u64 k = keys[i];
    if (k >= th){
      u32 pos = atomicAdd(&mcnt[e], 1u);
      u32 flat = 0xFFFFFFFFu - (u32)(k & 0xFFFFFFFFull);
      int t = (int)(flat >> 1);
      tokbuf[(size_t)e*CAP + pos] = t;
      wgtbuf[(size_t)e*CAP + pos] = __uint_as_float((u32)(k >> 32));
      u32 ic = atomicAdd(&invcnt[t], 1u);          // <=2 per token, distinct addrs
      inv[2*t + ic] = ((u32)e << 12) | pos;        // pos < 2560 fits 12 bits
    }
  }
}

// ---------- expert GEMMs, m97 structure ----------
__global__ __launch_bounds__(256) void k_gemm1(
    const ushort* __restrict__ xb, const ushort* __restrict__ wguT_g,
    const int* __restrict__ tok_g, const u32* __restrict__ mcnt_g,
    ushort* __restrict__ h_g){
  const int z = blockIdx.z;
  const int m_e = (int)mcnt_g[z];
  const int m0 = blockIdx.x * 128;
  if (m0 >= m_e) return;
  const ushort* wguT = wguT_g + (size_t)z*NGUPAD*CDIM;
  const int* tok = tok_g + (size_t)z*CAP;
  ushort* h = h_g + (size_t)z*CAP*IPAD;
  const int j0 = blockIdx.y * 64;

  __shared__ ushort As[128*32];
  __shared__ ushort Bg[64*32];
  __shared__ ushort Bu[64*32];
  const int tid = threadIdx.x;
  const int lane = tid & 63, wave = tid >> 6;
  const int wm = wave >> 1, wn = wave & 1;
  const int lm = lane & 15, quad = lane >> 4;

  const int af0 = tid*8, af1 = tid*8 + 2048;
  const ushort* ag0 = xb + (size_t)tok[m0 + (af0 >> 5)]*CDIM + (af0 & 31);
  const ushort* ag1 = xb + (size_t)tok[m0 + (af1 >> 5)]*CDIM + (af1 & 31);
  const int br = tid >> 2, bc = (tid & 3)*8;
  const ushort* bgp = wguT + (size_t)(j0 + br)*CDIM + bc;
  const ushort* bup = wguT + (size_t)(IPAD + j0 + br)*CDIM + bc;

  f32x4 accg[4][2], accu[4][2];
  #pragma unroll
  for (int i = 0; i < 4; ++i)
    #pragma unroll
    for (int j = 0; j < 2; ++j){
      accg[i][j] = (f32x4){0.f,0.f,0.f,0.f};
      accu[i][j] = (f32x4){0.f,0.f,0.f,0.f};
    }

  for (int k0 = 0; k0 < CDIM; k0 += 32){
    glds16(ag0 + k0, As + af0);
    glds16(ag1 + k0, As + af1);
    glds16(bgp + k0, Bg + tid*8);
    glds16(bup + k0, Bu + tid*8);
    __syncthreads();
    short8 a[4], vg[2], vu[2];
    #pragma unroll
    for (int mt = 0; mt < 4; ++mt)
      a[mt] = *(const short8*)(As + (wm*64 + mt*16 + lm)*32 + quad*8);
    #pragma unroll
    for (int nt = 0; nt < 2; ++nt){
      vg[nt] = *(const short8*)(Bg + (wn*32 + nt*16 + lm)*32 + quad*8);
      vu[nt] = *(const short8*)(Bu + (wn*32 + nt*16 + lm)*32 + quad*8);
    }
    __syncthreads();
    #pragma unroll
    for (int mt = 0; mt < 4; ++mt)
      #pragma unroll
      for (int nt = 0; nt < 2; ++nt){
        accg[mt][nt] = __builtin_amdgcn_mfma_f32_16x16x32_bf16(a[mt], vg[nt], accg[mt][nt], 0, 0, 0);
        accu[mt][nt] = __builtin_amdgcn_mfma_f32_16x16x32_bf16(a[mt], vu[nt], accu[mt][nt], 0, 0, 0);
      }
  }
  #pragma unroll
  for (int mt = 0; mt < 4; ++mt)
    #pragma unroll
    for (int nt = 0; nt < 2; ++nt)
      #pragma unroll
      for (int r = 0; r < 4; ++r){
        int row = m0 + wm*64 + mt*16 + quad*4 + r;
        int col = j0 + wn*32 + nt*16 + lm;
        float g = accg[mt][nt][r];
        float uu = accu[mt][nt][r];
        float sg = g / (1.f + __expf(-g));
        h[(size_t)row*IPAD + col] = f2bf(sg * uu);
      }
}

// Pure GEMM: y[e][slot][C] f32, plain stores. Round-3: tile 128x128 -> 128x64,
// grid 640 -> 1280 blocks (5.0/CU, no tail). Round-2 lesson: gemm2 at 640
// blocks was latency-bound (Occupancy 12%, MfmaUtil 13.5%) -- too few
// co-resident blocks to hide the per-iter glds16 drain.
__global__ __launch_bounds__(256) void k_gemm2(
    const ushort* __restrict__ h_g, const ushort* __restrict__ dwT_g,
    const u32* __restrict__ mcnt_g, float* __restrict__ y_g){
  const int z = blockIdx.z;
  const int m_e = (int)mcnt_g[z];
  const int m0 = blockIdx.x * 128;
  if (m0 >= m_e) return;
  const ushort* h = h_g + (size_t)z*CAP*IPAD;
  const ushort* dwT = dwT_g + (size_t)z*CDIM*IPAD;
  const int n0 = blockIdx.y * 64;

  __shared__ ushort As[128*32];
  __shared__ ushort Bs[64*32];
  const int tid = threadIdx.x;
  const int lane = tid & 63, wave = tid >> 6;
  const int wm = wave >> 1, wn = wave & 1;
  const int lm = lane & 15, quad = lane >> 4;

  const int af0 = tid*8, af1 = tid*8 + 2048;
  const ushort* ap0 = h + (size_t)(m0 + (af0 >> 5))*IPAD + (af0 & 31);
  const ushort* ap1 = h + (size_t)(m0 + (af1 >> 5))*IPAD + (af1 & 31);
  const int br = tid >> 2, bc = (tid & 3)*8;
  const ushort* bp = dwT + (size_t)(n0 + br)*IPAD + bc;

  f32x4 acc[4][2];
  #pragma unroll
  for (int i = 0; i < 4; ++i)
    #pragma unroll
    for (int j = 0; j < 2; ++j) acc[i][j] = (f32x4){0.f,0.f,0.f,0.f};

  for (int k0 = 0; k0 < IPAD; k0 += 32){
    glds16(ap0 + k0, As + af0);
    glds16(ap1 + k0, As + af1);
    glds16(bp + k0, Bs + tid*8);
    __syncthreads();
    short8 a[4], b[2];
    #pragma unroll
    for (int mt = 0; mt < 4; ++mt)
      a[mt] = *(const short8*)(As + (wm*64 + mt*16 + lm)*32 + quad*8);
    #pragma unroll
    for (int nt = 0; nt < 2; ++nt)
      b[nt] = *(const short8*)(Bs + (wn*32 + nt*16 + lm)*32 + quad*8);
    __syncthreads();
    #pragma unroll
    for (int mt = 0; mt < 4; ++mt)
      #pragma unroll
      for (int nt = 0; nt < 2; ++nt)
        acc[mt][nt] = __builtin_amdgcn_mfma_f32_16x16x32_bf16(a[mt], b[nt], acc[mt][nt], 0, 0, 0);
  }
  #pragma unroll
  for (int mt = 0; mt < 4; ++mt)
    #pragma unroll
    for (int r = 0; r < 4; ++r){
      int row = m0 + wm*64 + mt*16 + quad*4 + r;
      float* yrow = y_g + ((size_t)z*CAP + row)*CDIM;
      #pragma unroll
      for (int nt = 0; nt < 2; ++nt){
        int col = n0 + wn*32 + nt*16 + lm;
        yrow[col] = acc[mt][nt][r];
      }
    }
}

// Combine: out[t] = sum_j w_j * y[e_j][slot_j][:]. Writes every token row
// (tokens dropped by capacity -> zeros), so no out memset needed.
__global__ __launch_bounds__(256) void k_out(
    const float* __restrict__ ybuf, const u32* __restrict__ inv,
    const u32* __restrict__ invcnt, const float* __restrict__ wgtbuf,
    float* __restrict__ out){
  const int t = blockIdx.x*4 + (threadIdx.x >> 6);
  const int lane = threadIdx.x & 63;
  const int n = (int)invcnt[t];
  f32x4 acc[4];
  #pragma unroll
  for (int i = 0; i < 4; ++i) acc[i] = (f32x4){0.f,0.f,0.f,0.f};
  for (int j = 0; j < n; ++j){
    u32 v = inv[2*t + j];
    int e = (int)(v >> 12);
    int pos = (int)(v & 0xFFFu);
    float w = wgtbuf[e*CAP + pos];
    const float* yr = ybuf + ((size_t)e*CAP + pos)*CDIM;
    #pragma unroll
    for (int i = 0; i < 4; ++i){
      f32x4 yv = *(const f32x4*)(yr + i*256 + lane*4);
      acc[i] += yv * w;
    }
  }
  float* orow = out + (size_t)t*CDIM;
  #pragma unroll
  for (int i = 0; i < 4; ++i)
    *(f32x4*)(orow + i*256 + lane*4) = acc[i];
}

extern "C" void kernel_launch(void* const* d_in, const int* in_sizes, int n_in,
                              void* d_out, int out_size, void* d_ws, size_t ws_size,
                              hipStream_t stream){
  const float* x      = (const float*)d_in[0];
  const float* cond   = (const float*)d_in[1];
  const float* snr    = (const float*)d_in[2];
  const float* gate_w = (const float*)d_in[3];
  const float* wgu    = (const float*)d_in[4];
  const float* wdn    = (const float*)d_in[5];
  float* out = (float*)d_out;
  (void)in_sizes; (void)n_in; (void)ws_size; (void)out_size;

  char* ws = (char*)d_ws;
  size_t off = 0;
  auto take = [&](size_t bytes) -> char* {
    char* p = ws + off;
    off += (bytes + 255) & ~(size_t)255;
    return p;
  };
  u32* pcnt     = (u32*)take(8*CSTRIDE*4);   // 2048B, 256B-strided counters
  u32* mcnt     = (u32*)take(256);           // 8 x u32
  float* condlog = (float*)take(256);        // 32 x f32
  u64* thresh   = (u64*)take(256);           // 8 x u64
  u32* invcnt   = (u32*)take((size_t)T_TOK*4);     // 64KB, contiguous w/ ctrl
  u32* inv      = (u32*)take((size_t)T_TOK*2*4);   // 128KB (written before read)
  u64* entries  = (u64*)take((size_t)ENUM_*T_TOK*8);
  int* tokbuf   = (int*)take((size_t)ENUM_*CAP*4);
  float* wgtbuf = (float*)take((size_t)ENUM_*CAP*4);
  ushort* xb    = (ushort*)take((size_t)T_TOK*CDIM*2);
  ushort* wguT  = (ushort*)take((size_t)ENUM_*NGUPAD*CDIM*2);
  ushort* dwT   = (ushort*)take((size_t)ENUM_*CDIM*IPAD*2);
  ushort* hbuf  = (ushort*)take((size_t)EGRP*CAP*IPAD*2);
  float* ybuf   = (float*)take((size_t)ENUM_*CAP*CDIM*4);

  // pcnt..invcnt are contiguous takes: 2048+256+256+256+65536 = 68352 bytes
  hipMemsetAsync(pcnt, 0, 68352, stream);
  hipMemsetAsync(tokbuf, 0, (size_t)ENUM_*CAP*4, stream);  // padded slots -> token 0

  k_cond<<<4, 256, 0, stream>>>(cond, gate_w, condlog);
  k_gate<<<T_TOK/16, 256, 0, stream>>>(x, gate_w, condlog, snr, pcnt, entries, xb);
  k_tr_wgu<<<dim3(CDIM/32, NGUPAD/32, ENUM_), dim3(32,8), 0, stream>>>(wgu, wguT);
  k_tr_dwn<<<dim3(IPAD/32, CDIM/32, ENUM_), dim3(32,8), 0, stream>>>(wdn, dwT);
  k_select<<<ENUM_, 256, 0, stream>>>(pcnt, entries, thresh);
  k_compact<<<dim3(64, ENUM_), 256, 0, stream>>>(pcnt, entries, thresh, mcnt,
                                                 tokbuf, wgtbuf, invcnt, inv);

  for (int g = 0; g < ENUM_/EGRP; ++g){
    k_gemm1<<<dim3(CAP/128, IPAD/64, EGRP), 256, 0, stream>>>(
        xb, wguT + (size_t)g*EGRP*NGUPAD*CDIM,
        tokbuf + (size_t)g*EGRP*CAP, mcnt + g*EGRP, hbuf);
    k_gemm2<<<dim3(CAP/128, CDIM/64, EGRP), 256, 0, stream>>>(
        hbuf, dwT + (size_t)g*EGRP*CDIM*IPAD,
        mcnt + g*EGRP, ybuf + (size_t)g*EGRP*CAP*CDIM);
  }
  k_out<<<T_TOK/4, 256, 0, stream>>>(ybuf, inv, invcnt, wgtbuf, out);
}

// Round 4
// 1001.731 us; speedup vs baseline: 1.0555x; 1.0528x over previous
//
#include <hip/hip_runtime.h>
#include <hip/hip_bf16.h>
#include <stdint.h>

#define T_TOK 16384
#define CDIM  1024
#define ENUM_ 8
#define INTER_ 2730
#define IPAD  2816      // INTER padded to x128 (round-4: was 2752; 8-phase gemm1 needs N%128==0)
#define NGU   5460
#define NGUPAD 5632     // 2*IPAD: [g | u] each padded to 2816
#define CAP   2560
#define EGRP  4         // experts per GEMM dispatch (blockIdx.z)
#define CSTRIDE 64      // u32 stride between padded per-expert counters (256B)

typedef __attribute__((ext_vector_type(8))) short short8;
typedef __attribute__((ext_vector_type(4))) float f32x4;
typedef unsigned long long u64;
typedef unsigned int u32;

static __device__ __forceinline__ ushort f2bf(float f){
  u32 u = __float_as_uint(f);
  u32 r = u + 0x7FFFu + ((u >> 16) & 1u);
  return (ushort)(r >> 16);
}

// async global->LDS, 16B per lane. LDS dest = wave-uniform base + lane*16.
static __device__ __forceinline__ void glds16(const void* g, void* l){
  __builtin_amdgcn_global_load_lds(
      (const __attribute__((address_space(1))) void*)g,
      (__attribute__((address_space(3))) void*)l, 16, 0, 0);
}

// ---------- weight transposes ----------
__global__ void k_tr_wgu(const float* __restrict__ wgu, ushort* __restrict__ wguT){
  __shared__ float tile[32][33];
  const int e = blockIdx.z;
  const int k0 = blockIdx.x*32, n0 = blockIdx.y*32;
  const float* src = wgu + (size_t)e*CDIM*NGU;
  ushort* dst = wguT + (size_t)e*NGUPAD*CDIM;
  const int tx = threadIdx.x, ty = threadIdx.y;
  #pragma unroll
  for (int r = ty; r < 32; r += 8){
    int n = n0 + tx;
    int j = (n < IPAD) ? n : n - (IPAD - INTER_);
    bool valid = (n < INTER_) || (n >= IPAD && j < NGU);
    tile[r][tx] = valid ? src[(size_t)(k0 + r)*NGU + j] : 0.f;
  }
  __syncthreads();
  #pragma unroll
  for (int r = ty; r < 32; r += 8)
    dst[(size_t)(n0 + r)*CDIM + k0 + tx] = f2bf(tile[tx][r]);
}

__global__ void k_tr_dwn(const float* __restrict__ dw, ushort* __restrict__ dwT){
  __shared__ float tile[32][33];
  const int e = blockIdx.z;
  const int k0 = blockIdx.x*32, n0 = blockIdx.y*32;
  const float* src = dw + (size_t)e*INTER_*CDIM;
  ushort* dst = dwT + (size_t)e*CDIM*IPAD;
  const int tx = threadIdx.x, ty = threadIdx.y;
  #pragma unroll
  for (int r = ty; r < 32; r += 8){
    int k = k0 + r;
    tile[r][tx] = (k < INTER_) ? src[(size_t)k*CDIM + n0 + tx] : 0.f;
  }
  __syncthreads();
  #pragma unroll
  for (int r = ty; r < 32; r += 8)
    dst[(size_t)(n0 + r)*IPAD + k0 + tx] = f2bf(tile[tx][r]);
}

// ---------- gating ----------
__global__ void k_cond(const float* __restrict__ cond, const float* __restrict__ gate_w,
                       float* __restrict__ condlog){
  const int b = blockIdx.x;
  const int wave = threadIdx.x >> 6, lane = threadIdx.x & 63;
  float a0 = 0.f, a1 = 0.f;
  for (int c = lane; c < CDIM; c += 64){
    float cv = cond[(size_t)b*CDIM + c];
    const float* g = gate_w + (size_t)(CDIM + c)*8;
    a0 += cv * g[2*wave]; a1 += cv * g[2*wave + 1];
  }
  #pragma unroll
  for (int off = 32; off; off >>= 1){
    a0 += __shfl_down(a0, off, 64);
    a1 += __shfl_down(a1, off, 64);
  }
  if (lane == 0){
    condlog[b*8 + 2*wave]     = a0;
    condlog[b*8 + 2*wave + 1] = a1;
  }
}

// Gate logits with LDS-cached transposed gate_w. Block-aggregated atomics
// (round-1 win: 400us -> off the profile).
__global__ __launch_bounds__(256) void k_gate(
    const float* __restrict__ x, const float* __restrict__ gate_w,
    const float* __restrict__ condlog, const float* __restrict__ snr,
    u32* __restrict__ pcnt, u64* __restrict__ entries, ushort* __restrict__ xb){
  __shared__ float gwT[8*1024];
  __shared__ u32 lcnt[8];
  __shared__ u32 lbase[8];
  __shared__ u64 keybuf[32];
  __shared__ u32 posbuf[32];   // (expert<<16) | local_pos
  const int tid = threadIdx.x;
  if (tid < 8) lcnt[tid] = 0;
  for (int idx = tid; idx < 8192; idx += 256){
    float v = gate_w[idx];                    // coalesced read, [c][e] flat
    gwT[(idx & 7)*1024 + (idx >> 3)] = v;     // transpose into [e][c] (once)
  }
  __syncthreads();
  const int wave = tid >> 6, lane = tid & 63;
  const int tbase = blockIdx.x*16 + wave*4;
  #pragma unroll 1
  for (int it = 0; it < 4; ++it){
    const int t = tbase + it;
    const int b = t >> 12;                    // N = 4096 tokens/batch
    float acc[8] = {0,0,0,0,0,0,0,0};
    #pragma unroll
    for (int i = 0; i < 4; ++i){
      const int c = lane*4 + 256*i;
      const float4 xv = *(const float4*)(x + (size_t)t*CDIM + c);
      ushort4 xo;
      xo.x = f2bf(xv.x); xo.y = f2bf(xv.y); xo.z = f2bf(xv.z); xo.w = f2bf(xv.w);
      *(ushort4*)(xb + (size_t)t*CDIM + c) = xo;
      #pragma unroll
      for (int e = 0; e < 8; ++e){
        const float4 gv = *(const float4*)(gwT + e*1024 + c);
        acc[e] += xv.x*gv.x + xv.y*gv.y + xv.z*gv.z + xv.w*gv.w;
      }
    }
    #pragma unroll
    for (int e = 0; e < 8; ++e)
      #pragma unroll
      for (int off = 32; off; off >>= 1)
        acc[e] += __shfl_down(acc[e], off, 64);
    if (lane == 0){
      bool hn = snr[b] < 0.5f;
      float lg[8];
      #pragma unroll
      for (int e = 0; e < 8; ++e) lg[e] = acc[e] + condlog[b*8 + e];
      float mx = -1e30f;
      #pragma unroll
      for (int e = 0; e < 8; ++e) if (!(hn && e >= 2) && lg[e] > mx) mx = lg[e];
      float p[8]; float s = 0.f;
      #pragma unroll
      for (int e = 0; e < 8; ++e){ p[e] = (hn && e >= 2) ? 0.f : expf(lg[e] - mx); s += p[e]; }
      float inv_ = 1.f / s;
      #pragma unroll
      for (int e = 0; e < 8; ++e) p[e] *= inv_;
      int i0 = 0;
      #pragma unroll
      for (int e = 1; e < 8; ++e) if (p[e] > p[i0]) i0 = e;
      int i1 = -1; float pv1 = -1.f;
      #pragma unroll
      for (int e = 0; e < 8; ++e) if (e != i0 && p[e] > pv1){ pv1 = p[e]; i1 = e; }
      float v0 = p[i0], v1 = pv1;
      float den = fmaxf(v0 + v1, 1e-12f);
      v0 /= den; v1 /= den;
      u32 flat0 = (u32)(t*2);
      const int slot = wave*4 + it;
      u32 p0 = atomicAdd(&lcnt[i0], 1u);   // LDS atomic: fast, local
      u32 p1 = atomicAdd(&lcnt[i1], 1u);
      keybuf[2*slot]     = ((u64)__float_as_uint(v0) << 32) | (u64)(0xFFFFFFFFu - flat0);
      posbuf[2*slot]     = ((u32)i0 << 16) | p0;
      keybuf[2*slot + 1] = ((u64)__float_as_uint(v1) << 32) | (u64)(0xFFFFFFFFu - (flat0 + 1u));
      posbuf[2*slot + 1] = ((u32)i1 << 16) | p1;
    }
  }
  __syncthreads();
  if (tid < 8) lbase[tid] = atomicAdd(&pcnt[tid*CSTRIDE], lcnt[tid]);
  __syncthreads();
  if (tid < 32){
    u32 pe = posbuf[tid];
    int e = (int)(pe >> 16);
    u32 pos = pe & 0xFFFFu;
    entries[(size_t)e*T_TOK + lbase[e] + pos] = keybuf[tid];
  }
}

// ---------- capacity selection (exact top-k via unique 64b keys) ----------
__global__ void k_select(const u32* __restrict__ pcnt, const u64* __restrict__ entries,
                         u64* __restrict__ thresh){
  const int e = blockIdx.x;
  const int n = (int)pcnt[e*CSTRIDE];
  if (n <= CAP){ if (threadIdx.x == 0) thresh[e] = 0ull; return; }
  const u64* keys = entries + (size_t)e*T_TOK;
  __shared__ u32 hist[256];
  __shared__ u64 spfx;
  __shared__ int srem;
  u64 prefix = 0, pmask = 0;
  int rem = CAP;
  for (int d = 7; d >= 0; --d){
    const int sh = d*8;
    hist[threadIdx.x] = 0;
    __syncthreads();
    for (int i = threadIdx.x; i < n; i += 256){
      u64 k = keys[i];
      if ((k & pmask) == prefix)
        atomicAdd(&hist[(u32)((k >> sh) & 0xFFull)], 1u);
    }
    __syncthreads();
    if (threadIdx.x == 0){
      int c = 0, chosen = 0, nr = rem;
      for (int v = 255; v >= 0; --v){
        int nc = c + (int)hist[v];
        if (nc >= rem){ chosen = v; nr = rem - c; break; }
        c = nc;
      }
      spfx = prefix | ((u64)(u32)chosen << sh);
      srem = nr;
    }
    __syncthreads();
    prefix = spfx; rem = srem; pmask |= (0xFFull << sh);
  }
  if (threadIdx.x == 0) thresh[e] = prefix;
}

// Compact survivors AND build the inverse map (token -> up to 2 (e,slot)).
__global__ void k_compact(const u32* __restrict__ pcnt, const u64* __restrict__ entries,
                          const u64* __restrict__ thresh, u32* __restrict__ mcnt,
                          int* __restrict__ tokbuf, float* __restrict__ wgtbuf,
                          u32* __restrict__ invcnt, u32* __restrict__ inv){
  const int e = blockIdx.y;
  const int n = (int)pcnt[e*CSTRIDE];
  const u64 th = thresh[e];
  const u64* keys = entries + (size_t)e*T_TOK;
  for (int i = blockIdx.x*256 + threadIdx.x; i < n; i += gridDim.x*256){
    u64 k = keys[i];
    if (k >= th){
      u32 pos = atomicAdd(&mcnt[e], 1u);
      u32 flat = 0xFFFFFFFFu - (u32)(k & 0xFFFFFFFFull);
      int t = (int)(flat >> 1);
      tokbuf[(size_t)e*CAP + pos] = t;
      wgtbuf[(size_t)e*CAP + pos] = __uint_as_float((u32)(k >> 32));
      u32 ic = atomicAdd(&invcnt[t], 1u);          // <=2 per token, distinct addrs
      inv[2*t + ic] = ((u32)e << 12) | pos;        // pos < 2560 fits 12 bits
    }
  }
}

// ---------- gemm1: 256x(128 g/u-cols) 8-phase template (T2+T3+T4+T5) ----------
// BM=256, BK=64, 512 thr = 8 waves (4M x 2C); wave owns 64 rows x 64 h-cols,
// both g and u planes (B-tile 256 rows = [128 g | 128 u] -> silu fusion stays
// wave-local). LDS 128KB = 2 K-tile slots x (A 32KB + B 32KB), XOR-swizzle
// lb ^= ((lb>>7)&7)<<4 (8-way spread for stride-128B rows; reads 2-way = free).
// glds16 staging: linear LDS dest + inverse-swizzled per-lane global source
// (rule 21). Counted vmcnt(2) at phases 0/3/4/7 only -- never drained.
static __device__ __forceinline__ void mf16(f32x4 (&acc)[4][4],
                                            const short8 (&a)[4], const short8 (&b)[4]){
  #pragma unroll
  for (int mt = 0; mt < 4; ++mt)
    #pragma unroll
    for (int ct = 0; ct < 4; ++ct)
      acc[mt][ct] = __builtin_amdgcn_mfma_f32_16x16x32_bf16(a[mt], b[ct], acc[mt][ct], 0, 0, 0);
}

#define BAR do{ asm volatile("" ::: "memory"); __builtin_amdgcn_s_barrier(); \
                asm volatile("" ::: "memory"); }while(0)
#define VW2 asm volatile("s_waitcnt vmcnt(2)" ::: "memory")

__global__ __launch_bounds__(512, 2) void k_gemm1(
    const ushort* __restrict__ xb, const ushort* __restrict__ wguT_g,
    const int* __restrict__ tok_g, const u32* __restrict__ mcnt_g,
    ushort* __restrict__ h_g){
  const int z = blockIdx.z;
  const int m_e = (int)mcnt_g[z];
  const int m0 = blockIdx.x * 256;
  if (m0 >= m_e) return;
  const ushort* wguT = wguT_g + (size_t)z*NGUPAD*CDIM;
  const int* tok = tok_g + (size_t)z*CAP;
  ushort* h = h_g + (size_t)z*CAP*IPAD;
  const int j0 = blockIdx.y * 128;

  __shared__ __attribute__((aligned(128))) char lds[131072];
  const int tid = threadIdx.x;
  const int lane = tid & 63, wave = tid >> 6;
  const int wm = wave >> 1, wc = wave & 1;
  const int lm = lane & 15, quad = lane >> 4;

  // --- staging descriptors: dest d (linear) -> logical lb (inverse swizzle) ---
  const int d0 = tid*16, d1 = tid*16 + 8192;
  const int lb0 = d0 ^ (((d0 >> 7) & 7) << 4);
  const int lb1 = d1 ^ (((d1 >> 7) & 7) << 4);
  const int r0 = lb0 >> 7, c0 = (lb0 & 127) >> 1;
  const int r1 = lb1 >> 7, c1 = (lb1 & 127) >> 1;
  const ushort* ap00 = xb + (size_t)tok[m0 + r0]*CDIM + c0;        // A half 0
  const ushort* ap01 = xb + (size_t)tok[m0 + r1]*CDIM + c1;
  const ushort* ap10 = xb + (size_t)tok[m0 + 128 + r0]*CDIM + c0;  // A half 1
  const ushort* ap11 = xb + (size_t)tok[m0 + 128 + r1]*CDIM + c1;
  const ushort* bp00 = wguT + (size_t)(j0 + r0)*CDIM + c0;         // B plane g
  const ushort* bp01 = wguT + (size_t)(j0 + r1)*CDIM + c1;
  const ushort* bp10 = wguT + (size_t)(IPAD + j0 + r0)*CDIM + c0;  // B plane u
  const ushort* bp11 = wguT + (size_t)(IPAD + j0 + r1)*CDIM + c1;

#define STAGE_A(s, hf, ke) do{ \
    glds16(((hf) ? ap10 : ap00) + (ke), lds + (s)*32768 + (hf)*16384 + d0); \
    glds16(((hf) ? ap11 : ap01) + (ke), lds + (s)*32768 + (hf)*16384 + d1); }while(0)
#define STAGE_B(s, pl, ke) do{ \
    glds16(((pl) ? bp10 : bp00) + (ke), lds + 65536 + (s)*32768 + (pl)*16384 + d0); \
    glds16(((pl) ? bp11 : bp01) + (ke), lds + 65536 + (s)*32768 + (pl)*16384 + d1); }while(0)

  // --- fragment-read byte offsets (pre-swizzled) ---
  int aoff[4][2], boff[4][2];
  #pragma unroll
  for (int mt = 0; mt < 4; ++mt)
    #pragma unroll
    for (int ks = 0; ks < 2; ++ks){
      int lba = ((wm & 1)*64 + mt*16 + lm)*128 + ks*64 + quad*16;
      aoff[mt][ks] = (wm >> 1)*16384 + (lba ^ (((lba >> 7) & 7) << 4));
      int lbb = (wc*64 + mt*16 + lm)*128 + ks*64 + quad*16;
      boff[mt][ks] = lbb ^ (((lbb >> 7) & 7) << 4);
    }

#define RD(off) (*(const short8*)(lds + (off)))
#define LOAD_A(s, ks) do{ a[0]=RD((s)*32768+aoff[0][ks]); a[1]=RD((s)*32768+aoff[1][ks]); \
                          a[2]=RD((s)*32768+aoff[2][ks]); a[3]=RD((s)*32768+aoff[3][ks]); }while(0)
#define LOAD_B(s, pl, ks) do{ \
    b[0]=RD(65536+(s)*32768+(pl)*16384+boff[0][ks]); b[1]=RD(65536+(s)*32768+(pl)*16384+boff[1][ks]); \
    b[2]=RD(65536+(s)*32768+(pl)*16384+boff[2][ks]); b[3]=RD(65536+(s)*32768+(pl)*16384+boff[3][ks]); }while(0)

  f32x4 accg[4][4], accu[4][4];
  #pragma unroll
  for (int i = 0; i < 4; ++i)
    #pragma unroll
    for (int j = 0; j < 4; ++j){
      accg[i][j] = (f32x4){0.f,0.f,0.f,0.f};
      accu[i][j] = (f32x4){0.f,0.f,0.f,0.f};
    }
  short8 a[4], b[4];

  // prologue: stage kt0 into slot 0 (A-h0, A-h1, B-g, B-u = 8 loads)
  STAGE_A(0,0,0); STAGE_A(0,1,0); STAGE_B(0,0,0); STAGE_B(0,1,0);
  VW2;            // A-h0, A-h1, B-g landed (B-u covered by end-of-p0 wait)
  BAR;

  #pragma unroll 1
  for (int i = 0; i < CDIM/128; ++i){           // 8 iters, 2 K-tiles each
    const int ke1 = (2*i + 1)*64;               // kt for slot1 (this iter p4-7)
    const int ke2 = ((2*i + 2) & (CDIM/64 - 1))*64;  // kt for slot0 (next iter; wraps)
    // p0: g, ks0, slot0
    STAGE_A(1,0,ke1); LOAD_A(0,0); LOAD_B(0,0,0);
    BAR; __builtin_amdgcn_s_setprio(1); mf16(accg, a, b); __builtin_amdgcn_s_setprio(0); VW2; BAR;
    // p1: u, ks0 (A held in regs)
    STAGE_A(1,1,ke1); LOAD_B(0,1,0);
    BAR; __builtin_amdgcn_s_setprio(1); mf16(accu, a, b); __builtin_amdgcn_s_setprio(0); BAR;
    // p2: g, ks1
    STAGE_B(1,0,ke1); LOAD_A(0,1); LOAD_B(0,0,1);
    BAR; __builtin_amdgcn_s_setprio(1); mf16(accg, a, b); __builtin_amdgcn_s_setprio(0); BAR;
    // p3: u, ks1
    STAGE_B(1,1,ke1); LOAD_B(0,1,1);
    BAR; __builtin_amdgcn_s_setprio(1); mf16(accu, a, b); __builtin_amdgcn_s_setprio(0); VW2; BAR;
    // p4: g, ks0, slot1
    STAGE_A(0,0,ke2); LOAD_A(1,0); LOAD_B(1,0,0);
    BAR; __builtin_amdgcn_s_setprio(1); mf16(accg, a, b); __builtin_amdgcn_s_setprio(0); VW2; BAR;
    // p5: u, ks0
    STAGE_A(0,1,ke2); LOAD_B(1,1,0);
    BAR; __builtin_amdgcn_s_setprio(1); mf16(accu, a, b); __builtin_amdgcn_s_setprio(0); BAR;
    // p6: g, ks1
    STAGE_B(0,0,ke2); LOAD_A(1,1); LOAD_B(1,0,1);
    BAR; __builtin_amdgcn_s_setprio(1); mf16(accg, a, b); __builtin_amdgcn_s_setprio(0); BAR;
    // p7: u, ks1
    STAGE_B(0,1,ke2); LOAD_B(1,1,1);
    BAR; __builtin_amdgcn_s_setprio(1); mf16(accu, a, b); __builtin_amdgcn_s_setprio(0); VW2; BAR;
  }

  #pragma unroll
  for (int mt = 0; mt < 4; ++mt)
    #pragma unroll
    for (int ct = 0; ct < 4; ++ct)
      #pragma unroll
      for (int r = 0; r < 4; ++r){
        int row = m0 + wm*64 + mt*16 + quad*4 + r;
        int col = j0 + wc*64 + ct*16 + lm;
        float g = accg[mt][ct][r];
        float uu = accu[mt][ct][r];
        float sg = g / (1.f + __expf(-g));
        h[(size_t)row*IPAD + col] = f2bf(sg * uu);
      }
#undef STAGE_A
#undef STAGE_B
#undef RD
#undef LOAD_A
#undef LOAD_B
}

// Pure GEMM: y[e][slot][C] f32, plain stores (round-3 structure, 128x64 tile).
__global__ __launch_bounds__(256) void k_gemm2(
    const ushort* __restrict__ h_g, const ushort* __restrict__ dwT_g,
    const u32* __restrict__ mcnt_g, float* __restrict__ y_g){
  const int z = blockIdx.z;
  const int m_e = (int)mcnt_g[z];
  const int m0 = blockIdx.x * 128;
  if (m0 >= m_e) return;
  const ushort* h = h_g + (size_t)z*CAP*IPAD;
  const ushort* dwT = dwT_g + (size_t)z*CDIM*IPAD;
  const int n0 = blockIdx.y * 64;

  __shared__ ushort As[128*32];
  __shared__ ushort Bs[64*32];
  const int tid = threadIdx.x;
  const int lane = tid & 63, wave = tid >> 6;
  const int wm = wave >> 1, wn = wave & 1;
  const int lm = lane & 15, quad = lane >> 4;

  const int af0 = tid*8, af1 = tid*8 + 2048;
  const ushort* ap0 = h + (size_t)(m0 + (af0 >> 5))*IPAD + (af0 & 31);
  const ushort* ap1 = h + (size_t)(m0 + (af1 >> 5))*IPAD + (af1 & 31);
  const int br = tid >> 2, bc = (tid & 3)*8;
  const ushort* bp = dwT + (size_t)(n0 + br)*IPAD + bc;

  f32x4 acc[4][2];
  #pragma unroll
  for (int i = 0; i < 4; ++i)
    #pragma unroll
    for (int j = 0; j < 2; ++j) acc[i][j] = (f32x4){0.f,0.f,0.f,0.f};

  for (int k0 = 0; k0 < IPAD; k0 += 32){
    glds16(ap0 + k0, As + af0);
    glds16(ap1 + k0, As + af1);
    glds16(bp + k0, Bs + tid*8);
    __syncthreads();
    short8 a[4], b[2];
    #pragma unroll
    for (int mt = 0; mt < 4; ++mt)
      a[mt] = *(const short8*)(As + (wm*64 + mt*16 + lm)*32 + quad*8);
    #pragma unroll
    for (int nt = 0; nt < 2; ++nt)
      b[nt] = *(const short8*)(Bs + (wn*32 + nt*16 + lm)*32 + quad*8);
    __syncthreads();
    #pragma unroll
    for (int mt = 0; mt < 4; ++mt)
      #pragma unroll
      for (int nt = 0; nt < 2; ++nt)
        acc[mt][nt] = __builtin_amdgcn_mfma_f32_16x16x32_bf16(a[mt], b[nt], acc[mt][nt], 0, 0, 0);
  }
  #pragma unroll
  for (int mt = 0; mt < 4; ++mt)
    #pragma unroll
    for (int r = 0; r < 4; ++r){
      int row = m0 + wm*64 + mt*16 + quad*4 + r;
      float* yrow = y_g + ((size_t)z*CAP + row)*CDIM;
      #pragma unroll
      for (int nt = 0; nt < 2; ++nt){
        int col = n0 + wn*32 + nt*16 + lm;
        yrow[col] = acc[mt][nt][r];
      }
    }
}

// Combine: out[t] = sum_j w_j * y[e_j][slot_j][:].
__global__ __launch_bounds__(256) void k_out(
    const float* __restrict__ ybuf, const u32* __restrict__ inv,
    const u32* __restrict__ invcnt, const float* __restrict__ wgtbuf,
    float* __restrict__ out){
  const int t = blockIdx.x*4 + (threadIdx.x >> 6);
  const int lane = threadIdx.x & 63;
  const int n = (int)invcnt[t];
  f32x4 acc[4];
  #pragma unroll
  for (int i = 0; i < 4; ++i) acc[i] = (f32x4){0.f,0.f,0.f,0.f};
  for (int j = 0; j < n; ++j){
    u32 v = inv[2*t + j];
    int e = (int)(v >> 12);
    int pos = (int)(v & 0xFFFu);
    float w = wgtbuf[e*CAP + pos];
    const float* yr = ybuf + ((size_t)e*CAP + pos)*CDIM;
    #pragma unroll
    for (int i = 0; i < 4; ++i){
      f32x4 yv = *(const f32x4*)(yr + i*256 + lane*4);
      acc[i] += yv * w;
    }
  }
  float* orow = out + (size_t)t*CDIM;
  #pragma unroll
  for (int i = 0; i < 4; ++i)
    *(f32x4*)(orow + i*256 + lane*4) = acc[i];
}

extern "C" void kernel_launch(void* const* d_in, const int* in_sizes, int n_in,
                              void* d_out, int out_size, void* d_ws, size_t ws_size,
                              hipStream_t stream){
  const float* x      = (const float*)d_in[0];
  const float* cond   = (const float*)d_in[1];
  const float* snr    = (const float*)d_in[2];
  const float* gate_w = (const float*)d_in[3];
  const float* wgu    = (const float*)d_in[4];
  const float* wdn    = (const float*)d_in[5];
  float* out = (float*)d_out;
  (void)in_sizes; (void)n_in; (void)ws_size; (void)out_size;

  char* ws = (char*)d_ws;
  size_t off = 0;
  auto take = [&](size_t bytes) -> char* {
    char* p = ws + off;
    off += (bytes + 255) & ~(size_t)255;
    return p;
  };
  u32* pcnt     = (u32*)take(8*CSTRIDE*4);   // 2048B, 256B-strided counters
  u32* mcnt     = (u32*)take(256);           // 8 x u32
  float* condlog = (float*)take(256);        // 32 x f32
  u64* thresh   = (u64*)take(256);           // 8 x u64
  u32* invcnt   = (u32*)take((size_t)T_TOK*4);     // 64KB, contiguous w/ ctrl
  u32* inv      = (u32*)take((size_t)T_TOK*2*4);   // 128KB (written before read)
  u64* entries  = (u64*)take((size_t)ENUM_*T_TOK*8);
  int* tokbuf   = (int*)take((size_t)ENUM_*CAP*4);
  float* wgtbuf = (float*)take((size_t)ENUM_*CAP*4);
  ushort* xb    = (ushort*)take((size_t)T_TOK*CDIM*2);
  ushort* wguT  = (ushort*)take((size_t)ENUM_*NGUPAD*CDIM*2);
  ushort* dwT   = (ushort*)take((size_t)ENUM_*CDIM*IPAD*2);
  ushort* hbuf  = (ushort*)take((size_t)EGRP*CAP*IPAD*2);
  float* ybuf   = (float*)take((size_t)ENUM_*CAP*CDIM*4);

  // pcnt..invcnt are contiguous takes: 2048+256+256+256+65536 = 68352 bytes
  hipMemsetAsync(pcnt, 0, 68352, stream);
  hipMemsetAsync(tokbuf, 0, (size_t)ENUM_*CAP*4, stream);  // padded slots -> token 0

  k_cond<<<4, 256, 0, stream>>>(cond, gate_w, condlog);
  k_gate<<<T_TOK/16, 256, 0, stream>>>(x, gate_w, condlog, snr, pcnt, entries, xb);
  k_tr_wgu<<<dim3(CDIM/32, NGUPAD/32, ENUM_), dim3(32,8), 0, stream>>>(wgu, wguT);
  k_tr_dwn<<<dim3(IPAD/32, CDIM/32, ENUM_), dim3(32,8), 0, stream>>>(wdn, dwT);
  k_select<<<ENUM_, 256, 0, stream>>>(pcnt, entries, thresh);
  k_compact<<<dim3(64, ENUM_), 256, 0, stream>>>(pcnt, entries, thresh, mcnt,
                                                 tokbuf, wgtbuf, invcnt, inv);

  for (int g = 0; g < ENUM_/EGRP; ++g){
    k_gemm1<<<dim3(CAP/256, IPAD/128, EGRP), 512, 0, stream>>>(
        xb, wguT + (size_t)g*EGRP*NGUPAD*CDIM,
        tokbuf + (size_t)g*EGRP*CAP, mcnt + g*EGRP, hbuf);
    k_gemm2<<<dim3(CAP/128, CDIM/64, EGRP), 256, 0, stream>>>(
        hbuf, dwT + (size_t)g*EGRP*CDIM*IPAD,
        mcnt + g*EGRP, ybuf + (size_t)g*EGRP*CAP*CDIM);
  }
  k_out<<<T_TOK/4, 256, 0, stream>>>(ybuf, inv, invcnt, wgtbuf, out);
}